// Round 2
// baseline (124.664 us; speedup 1.0000x reference)
//
#include <hip/hip_runtime.h>

// Problem constants (fixed by the reference file).
#define GH 7
#define GW 7
#define HIMG 256
#define WIMG 256
#define CIMG 256
#define NBOXES 1000
#define NCELLS (NBOXES * GH * GW)   // 49000

// One wave (64 lanes) per output cell (box, gy, gx); each lane does 4
// channels via float4. NHWC layout => channel dim contiguous, so each
// pixel read is 64 lanes x 16B = 1KB fully coalesced.
__global__ __launch_bounds__(256) void roi_kernel(
    const float* __restrict__ meta,
    const float* __restrict__ img,
    const float* __restrict__ boxes,
    float* __restrict__ out)
{
    const int wave = threadIdx.x >> 6;
    const int lane = threadIdx.x & 63;
    const int cell = blockIdx.x * 4 + wave;       // 0..48999 (exact multiple)

    const int b  = cell / (GH * GW);
    const int g  = cell - b * (GH * GW);
    const int gy = g / GW;
    const int gx = g - gy * GW;

    // metadata = [h, w, 1.0]; reference normalizes by (w-1)/(h-1) then
    // multiplies by (H_IMG-1)/(W_IMG-1). Replicate both steps.
    const float h = meta[0];
    const float w = meta[1];

    const float bx1 = boxes[b * 4 + 0] / (w - 1.0f);
    const float by1 = boxes[b * 4 + 1] / (h - 1.0f);
    const float bx2 = boxes[b * 4 + 2] / (w - 1.0f);
    const float by2 = boxes[b * 4 + 3] / (h - 1.0f);

    const float ty = (float)gy / (float)(GH - 1);
    const float tx = (float)gx / (float)(GW - 1);

    const float in_y = (by1 + ty * (by2 - by1)) * (float)(HIMG - 1);
    const float in_x = (bx1 + tx * (bx2 - bx1)) * (float)(WIMG - 1);

    const bool valid = (in_y >= 0.0f) && (in_y <= (float)(HIMG - 1)) &&
                       (in_x >= 0.0f) && (in_x <= (float)(WIMG - 1));

    const float y0f = floorf(in_y);
    const float x0f = floorf(in_x);
    const float ly = in_y - y0f;
    const float lx = in_x - x0f;

    const int y0 = (int)fminf(fmaxf(y0f,        0.0f), (float)(HIMG - 1));
    const int y1 = (int)fminf(fmaxf(y0f + 1.0f, 0.0f), (float)(HIMG - 1));
    const int x0 = (int)fminf(fmaxf(x0f,        0.0f), (float)(WIMG - 1));
    const int x1 = (int)fminf(fmaxf(x0f + 1.0f, 0.0f), (float)(WIMG - 1));

    const float4* p00 = (const float4*)(img + (size_t)(y0 * WIMG + x0) * CIMG) + lane;
    const float4* p01 = (const float4*)(img + (size_t)(y0 * WIMG + x1) * CIMG) + lane;
    const float4* p10 = (const float4*)(img + (size_t)(y1 * WIMG + x0) * CIMG) + lane;
    const float4* p11 = (const float4*)(img + (size_t)(y1 * WIMG + x1) * CIMG) + lane;

    const float4 g00 = *p00;
    const float4 g01 = *p01;
    const float4 g10 = *p10;
    const float4 g11 = *p11;

    const float omlx = 1.0f - lx;
    const float omly = 1.0f - ly;

    float4 o;
    // Replicate reference blend order: top = g00*(1-lx)+g01*lx; bot likewise;
    // out = top*(1-ly) + bot*ly.
    o.x = (g00.x * omlx + g01.x * lx) * omly + (g10.x * omlx + g11.x * lx) * ly;
    o.y = (g00.y * omlx + g01.y * lx) * omly + (g10.y * omlx + g11.y * lx) * ly;
    o.z = (g00.z * omlx + g01.z * lx) * omly + (g10.z * omlx + g11.z * lx) * ly;
    o.w = (g00.w * omlx + g01.w * lx) * omly + (g10.w * omlx + g11.w * lx) * ly;

    if (!valid) {
        o.x = 0.0f; o.y = 0.0f; o.z = 0.0f; o.w = 0.0f;
    }

    float4* op = (float4*)(out + (size_t)cell * CIMG) + lane;
    *op = o;
}

extern "C" void kernel_launch(void* const* d_in, const int* in_sizes, int n_in,
                              void* d_out, int out_size, void* d_ws, size_t ws_size,
                              hipStream_t stream) {
    const float* meta  = (const float*)d_in[0];
    const float* img   = (const float*)d_in[1];
    const float* boxes = (const float*)d_in[2];
    float* out = (float*)d_out;

    // 4 cells (waves) per 256-thread block; 49000 / 4 = 12250 exactly.
    dim3 grid(NCELLS / 4);
    dim3 block(256);
    roi_kernel<<<grid, block, 0, stream>>>(meta, img, boxes, out);
}

// Round 4
// 123.847 us; speedup vs baseline: 1.0066x; 1.0066x over previous
//
#include <hip/hip_runtime.h>

// Problem constants (fixed by the reference file).
#define GH 7
#define GW 7
#define HIMG 256
#define WIMG 256
#define CIMG 256
#define NBOXES 1000
#define NCELLS (NBOXES * GH * GW)   // 49000

// Native clang vector type: __builtin_nontemporal_store requires a real
// vector type, not HIP's HIP_vector_type<float,4> class.
typedef float f32x4 __attribute__((ext_vector_type(4)));

// One wave (64 lanes) per output cell (box, gy, gx); each lane does 4
// channels via float4. NHWC layout => channel dim contiguous, so each
// pixel read is 64 lanes x 16B = 1KB fully coalesced.
// Output is written with nontemporal stores: it is never re-read, and
// letting the 50MB write stream allocate in L2 evicts image lines that
// have ~3x average reuse.
__global__ __launch_bounds__(256) void roi_kernel(
    const float* __restrict__ meta,
    const float* __restrict__ img,
    const float* __restrict__ boxes,
    float* __restrict__ out)
{
    const int wave = threadIdx.x >> 6;
    const int lane = threadIdx.x & 63;
    const int cell = blockIdx.x * 4 + wave;       // 0..48999 (exact multiple)

    const int b  = cell / (GH * GW);
    const int g  = cell - b * (GH * GW);
    const int gy = g / GW;
    const int gx = g - gy * GW;

    // metadata = [h, w, 1.0]; reference normalizes by (w-1)/(h-1) then
    // multiplies by (H_IMG-1)/(W_IMG-1). Replicate both steps.
    const float h = meta[0];
    const float w = meta[1];

    const float bx1 = boxes[b * 4 + 0] / (w - 1.0f);
    const float by1 = boxes[b * 4 + 1] / (h - 1.0f);
    const float bx2 = boxes[b * 4 + 2] / (w - 1.0f);
    const float by2 = boxes[b * 4 + 3] / (h - 1.0f);

    const float ty = (float)gy / (float)(GH - 1);
    const float tx = (float)gx / (float)(GW - 1);

    const float in_y = (by1 + ty * (by2 - by1)) * (float)(HIMG - 1);
    const float in_x = (bx1 + tx * (bx2 - bx1)) * (float)(WIMG - 1);

    const bool valid = (in_y >= 0.0f) && (in_y <= (float)(HIMG - 1)) &&
                       (in_x >= 0.0f) && (in_x <= (float)(WIMG - 1));

    const float y0f = floorf(in_y);
    const float x0f = floorf(in_x);
    const float ly = in_y - y0f;
    const float lx = in_x - x0f;

    const int y0 = (int)fminf(fmaxf(y0f,        0.0f), (float)(HIMG - 1));
    const int y1 = (int)fminf(fmaxf(y0f + 1.0f, 0.0f), (float)(HIMG - 1));
    const int x0 = (int)fminf(fmaxf(x0f,        0.0f), (float)(WIMG - 1));
    const int x1 = (int)fminf(fmaxf(x0f + 1.0f, 0.0f), (float)(WIMG - 1));

    const f32x4* p00 = (const f32x4*)(img + (size_t)(y0 * WIMG + x0) * CIMG) + lane;
    const f32x4* p01 = (const f32x4*)(img + (size_t)(y0 * WIMG + x1) * CIMG) + lane;
    const f32x4* p10 = (const f32x4*)(img + (size_t)(y1 * WIMG + x0) * CIMG) + lane;
    const f32x4* p11 = (const f32x4*)(img + (size_t)(y1 * WIMG + x1) * CIMG) + lane;

    const f32x4 g00 = *p00;
    const f32x4 g01 = *p01;
    const f32x4 g10 = *p10;
    const f32x4 g11 = *p11;

    const float omlx = 1.0f - lx;
    const float omly = 1.0f - ly;

    // Replicate reference blend order: top = g00*(1-lx)+g01*lx; bot likewise;
    // out = top*(1-ly) + bot*ly.
    f32x4 o = (g00 * omlx + g01 * lx) * omly + (g10 * omlx + g11 * lx) * ly;

    if (!valid) {
        o = (f32x4)0.0f;
    }

    f32x4* op = (f32x4*)(out + (size_t)cell * CIMG) + lane;
    __builtin_nontemporal_store(o, op);
}

extern "C" void kernel_launch(void* const* d_in, const int* in_sizes, int n_in,
                              void* d_out, int out_size, void* d_ws, size_t ws_size,
                              hipStream_t stream) {
    const float* meta  = (const float*)d_in[0];
    const float* img   = (const float*)d_in[1];
    const float* boxes = (const float*)d_in[2];
    float* out = (float*)d_out;

    // 4 cells (waves) per 256-thread block; 49000 / 4 = 12250 exactly.
    dim3 grid(NCELLS / 4);
    dim3 block(256);
    roi_kernel<<<grid, block, 0, stream>>>(meta, img, boxes, out);
}